// Round 10
// baseline (676.042 us; speedup 1.0000x reference)
//
#include <hip/hip_runtime.h>

// Graph-transformer MHA layer. N=50000, E=1600000, IN_DIM=64, H=8, D=8.
// Outputs: h_out [N*64] then e_out [E*64], fp32, concatenated in d_out.
//
// R10: decouple permutation from compute.
//  - edge kernel: NO atomics, NO scattered writes. Gates written coalesced to
//    sg[eid*8+head]. (R9's in-kernel slot atomic-with-return stalled each wave
//    on a cross-XCD RMW; its 32B random scatters cost ~2x RFO traffic.)
//  - slot_kernel: perm[atomicAdd(cursor[dst[i]],1)] = i  — lean, huge TLP,
//    RMW latency hidden by independent threads.
//  - aggregate: ei = perm[j]; gates via sg[ei*8+head] (L3-resident re-reads).

using short8 = __attribute__((ext_vector_type(8))) short;
using f32x16 = __attribute__((ext_vector_type(16))) float;

__device__ __forceinline__ short f2bf(float f) {
    unsigned u = __builtin_bit_cast(unsigned, f);
    u += 0x7FFF + ((u >> 16) & 1);          // RNE to bf16
    return (short)(u >> 16);
}

// ---------------- node projection ----------------
__global__ __launch_bounds__(256)
void proj_kernel(const float* __restrict__ hsrc,
                 const float* __restrict__ Wq, const float* __restrict__ bq,
                 const float* __restrict__ Wk, const float* __restrict__ bk,
                 const float* __restrict__ Wv, const float* __restrict__ bv,
                 float* __restrict__ Q, float* __restrict__ K, float* __restrict__ V,
                 int n)
{
    const float* W;
    const float* b;
    float* out;
    if (blockIdx.y == 0)      { W = Wq; b = bq; out = Q; }
    else if (blockIdx.y == 1) { W = Wk; b = bk; out = K; }
    else                      { W = Wv; b = bv; out = V; }

    const int t    = threadIdx.x;
    const int lane = t & 63;
    const int w    = t >> 6;

    float wcol[64];
#pragma unroll
    for (int k = 0; k < 64; ++k) wcol[k] = W[k * 64 + lane];
    const float bias = b[lane];

    __shared__ float4 sh[16][16];
    const float4* __restrict__ h4 = (const float4*)hsrc;

    const int ngroups = (n + 15) >> 4;
    for (int g = blockIdx.x; g < ngroups; g += gridDim.x) {
        const int base = g << 4;
        {
            const int rs = t >> 4, c4 = t & 15;
            float4 v = make_float4(0.f, 0.f, 0.f, 0.f);
            if (base + rs < n) v = h4[(size_t)(base + rs) * 16 + c4];
            __syncthreads();
            sh[rs][c4] = v;
            __syncthreads();
        }
        float acc0 = bias, acc1 = bias, acc2 = bias, acc3 = bias;
#pragma unroll
        for (int k4 = 0; k4 < 16; ++k4) {
            const float w0 = wcol[k4 * 4 + 0], w1 = wcol[k4 * 4 + 1];
            const float w2 = wcol[k4 * 4 + 2], w3 = wcol[k4 * 4 + 3];
            const float4 a = sh[w * 4 + 0][k4];
            const float4 bb = sh[w * 4 + 1][k4];
            const float4 c = sh[w * 4 + 2][k4];
            const float4 d = sh[w * 4 + 3][k4];
            acc0 = fmaf(a.w,  w3, fmaf(a.z,  w2, fmaf(a.y,  w1, fmaf(a.x,  w0, acc0))));
            acc1 = fmaf(bb.w, w3, fmaf(bb.z, w2, fmaf(bb.y, w1, fmaf(bb.x, w0, acc1))));
            acc2 = fmaf(c.w,  w3, fmaf(c.z,  w2, fmaf(c.y,  w1, fmaf(c.x,  w0, acc2))));
            acc3 = fmaf(d.w,  w3, fmaf(d.z,  w2, fmaf(d.y,  w1, fmaf(d.x,  w0, acc3))));
        }
        const int n0 = base + w * 4;
        if (n0 + 0 < n) out[(size_t)(n0 + 0) * 64 + lane] = acc0;
        if (n0 + 1 < n) out[(size_t)(n0 + 1) * 64 + lane] = acc1;
        if (n0 + 2 < n) out[(size_t)(n0 + 2) * 64 + lane] = acc2;
        if (n0 + 3 < n) out[(size_t)(n0 + 3) * 64 + lane] = acc3;
    }
}

// ---------------- dst histogram ----------------
__global__ __launch_bounds__(256)
void hist_kernel(const int* __restrict__ dst, int* __restrict__ counts, int E)
{
    int i = blockIdx.x * 256 + threadIdx.x;
    const int stride = gridDim.x * 256;
    for (; i < E; i += stride) atomicAdd(&counts[dst[i]], 1);
}

// ---------------- multi-block exclusive scan (3 kernels) ----------------
__global__ __launch_bounds__(1024)
void scan1_kernel(const int* __restrict__ counts, int* __restrict__ offsets,
                  int* __restrict__ bsum, int n)
{
    const int t = threadIdx.x;
    const int lane = t & 63;
    const int w = t >> 6;
    __shared__ int wsum[16];
    const int i = blockIdx.x * 1024 + t;
    const int v = (i < n) ? counts[i] : 0;
    int x = v;
#pragma unroll
    for (int d = 1; d < 64; d <<= 1) {
        int y = __shfl_up(x, d);
        if (lane >= d) x += y;
    }
    if (lane == 63) wsum[w] = x;
    __syncthreads();
    if (w == 0 && lane < 16) {
        int s = wsum[lane];
#pragma unroll
        for (int d = 1; d < 16; d <<= 1) {
            int y = __shfl_up(s, d);
            if (lane >= d) s += y;
        }
        wsum[lane] = s;
    }
    __syncthreads();
    const int excl = ((w == 0) ? 0 : wsum[w - 1]) + (x - v);
    if (i < n) offsets[i] = excl;
    if (t == 1023) bsum[blockIdx.x] = excl + v;
}

__global__ __launch_bounds__(64)
void scan2_kernel(int* __restrict__ bsum, int nb)
{
    const int lane = threadIdx.x;
    const int v = (lane < nb) ? bsum[lane] : 0;
    int x = v;
#pragma unroll
    for (int d = 1; d < 64; d <<= 1) {
        int y = __shfl_up(x, d);
        if (lane >= d) x += y;
    }
    if (lane < nb) bsum[lane] = x - v;   // exclusive
}

__global__ __launch_bounds__(1024)
void scan3_kernel(int* __restrict__ offsets, int* __restrict__ cursor,
                  const int* __restrict__ bsum, int n, int E)
{
    const int i = blockIdx.x * 1024 + threadIdx.x;
    if (i < n) {
        const int off = offsets[i] + bsum[blockIdx.x];
        offsets[i] = off;
        cursor[i] = off;
    }
    if (blockIdx.x == 0 && threadIdx.x == 0) offsets[n] = E;
}

// ---------------- slot kernel: build dst-sorted permutation ----------------
__global__ __launch_bounds__(256)
void slot_kernel(const int* __restrict__ dst, int* __restrict__ cursor,
                 int* __restrict__ perm, int E)
{
    int i = blockIdx.x * 256 + threadIdx.x;
    const int stride = gridDim.x * 256;
    for (; i < E; i += stride) {
        const int pos = atomicAdd(&cursor[dst[i]], 1);
        perm[pos] = i;
    }
}

// ---------------- edge kernel v10: MFMA, no atomics, coalesced gates ----------------
__global__ __launch_bounds__(256)
void edge_kernel(const float* __restrict__ e,
                 const float* __restrict__ We, const float* __restrict__ be,
                 const int* __restrict__ src, const int* __restrict__ dst,
                 const float* __restrict__ Q, const float* __restrict__ K,
                 float* __restrict__ e_out, float* __restrict__ sg, int E)
{
    __shared__ float4 tile4[4][32 * 8];             // 4KB per wave, XOR-swizzled
    const int t    = threadIdx.x;
    const int lane = t & 63;
    const int wu   = __builtin_amdgcn_readfirstlane(t >> 6);
    const int lid  = lane & 31;
    const int hi   = lane >> 5;
    float4* const myT4 = tile4[wu];
    const float inv = 0.35355339059327373f;         // 1/sqrt(8)

    // A fragments (We^T), loaded once per wave. A[jh][ks] elem (4g+i) holds
    // We[k = 16ks + 8g + 4hi + i][j = 32jh + lid].
    short8 Afr[2][4];
#pragma unroll
    for (int jh = 0; jh < 2; ++jh)
#pragma unroll
        for (int ks = 0; ks < 4; ++ks)
#pragma unroll
            for (int g = 0; g < 2; ++g)
#pragma unroll
                for (int i = 0; i < 4; ++i)
                    Afr[jh][ks][4 * g + i] =
                        f2bf(We[(16 * ks + 8 * g + 4 * hi + i) * 64 + 32 * jh + lid]);

    const int ntiles = (E + 63) >> 6;
    for (int tb = blockIdx.x * 4 + wu; tb < ntiles; tb += gridDim.x * 4) {
        const int base = tb << 6;

#pragma unroll
        for (int eh = 0; eh < 2; ++eh) {
            const int erow_i = base + eh * 32 + lid;
            const int erc = erow_i < E ? erow_i : (E - 1);
            const int se = src[erc];
            const int de = dst[erc];

            // B fragments: elem (4g+i) = e[row][k = 16ks + 8g + 4hi + i]
            const float* er = e + (size_t)erc * 64 + 4 * hi;
            short8 Bfr[4];
#pragma unroll
            for (int ks = 0; ks < 4; ++ks) {
                const float4 p0 = *(const float4*)(er + 16 * ks);
                const float4 p1 = *(const float4*)(er + 16 * ks + 8);
                Bfr[ks][0] = f2bf(p0.x); Bfr[ks][1] = f2bf(p0.y);
                Bfr[ks][2] = f2bf(p0.z); Bfr[ks][3] = f2bf(p0.w);
                Bfr[ks][4] = f2bf(p1.x); Bfr[ks][5] = f2bf(p1.y);
                Bfr[ks][6] = f2bf(p1.z); Bfr[ks][7] = f2bf(p1.w);
            }

            float gate[8];
#pragma unroll
            for (int jh = 0; jh < 2; ++jh) {
                f32x16 D = {};
#pragma unroll
                for (int ks = 0; ks < 4; ++ks)
                    D = __builtin_amdgcn_mfma_f32_32x32x16_bf16(
                            Afr[jh][ks], Bfr[ks], D, 0, 0, 0);

                // previous phase's LDS reads must be done before overwrite
                asm volatile("s_waitcnt lgkmcnt(0)" ::: "memory");

                // epilogue: JIT kv/qv/bev loads per hd; stage + head sums
                const float* kb = K + (size_t)se * 64 + 32 * jh + 4 * hi;
                const float* qb = Q + (size_t)de * 64 + 32 * jh + 4 * hi;
#pragma unroll
                for (int hd = 0; hd < 4; ++hd) {
                    const float4 kv  = *(const float4*)(kb + 8 * hd);
                    const float4 qv  = *(const float4*)(qb + 8 * hd);
                    const float4 bev = *(const float4*)(be + 32 * jh + 8 * hd + 4 * hi);
                    // reg r = 4*hd + i  ->  j_local(within jh) = 8*hd + 4*hi + i
                    const float s0 = kv.x * qv.x * inv * (D[4 * hd + 0] + bev.x);
                    const float s1 = kv.y * qv.y * inv * (D[4 * hd + 1] + bev.y);
                    const float s2 = kv.z * qv.z * inv * (D[4 * hd + 2] + bev.z);
                    const float s3 = kv.w * qv.w * inv * (D[4 * hd + 3] + bev.w);
                    const int c4 = (2 * hd + hi) ^ (lid & 7);       // XOR swizzle
                    myT4[lid * 8 + c4] = make_float4(s0, s1, s2, s3);
                    float p = (s0 + s1) + (s2 + s3);
                    const float full = p + __shfl_xor(p, 32);       // head = 4jh+hd
                    gate[jh * 4 + hd] = expf(fminf(fmaxf(full, -5.f), 5.f));
                }

                // readout: 4 x 64-lane dwordx4 stores of 128B half-rows
                const int r8 = lane >> 3, m = lane & 7;
#pragma unroll
                for (int it = 0; it < 4; ++it) {
                    const int row = it * 8 + r8;                    // edge row 0..31
                    const int edge2 = base + eh * 32 + row;
                    const float4 v = myT4[row * 8 + (m ^ (row & 7))];
                    if (edge2 < E)
                        *((float4*)e_out + (size_t)edge2 * 16 + jh * 8 + m) = v;
                }
            }

            // coalesced gate write: 32 edges x 32B contiguous (1KB per phase)
            if (erow_i < E) {
                const float4 g = (hi == 0)
                    ? make_float4(gate[0], gate[1], gate[2], gate[3])
                    : make_float4(gate[4], gate[5], gate[6], gate[7]);
                *(float4*)(sg + (size_t)erow_i * 8 + hi * 4) = g;
            }
        }
    }
}

// ---------------- aggregation: one wave per node, perm-gathered ----------------
__global__ __launch_bounds__(256)
void aggregate_kernel(const int* __restrict__ offsets,
                      const int* __restrict__ perm,
                      const int* __restrict__ src,
                      const float* __restrict__ sg,
                      const float* __restrict__ V,
                      float* __restrict__ hout, int n)
{
    const int w = (blockIdx.x * 256 + threadIdx.x) >> 6;
    const int lane = threadIdx.x & 63;
    if (w >= n) return;
    const int o0 = offsets[w], o1 = offsets[w + 1];
    const int head = lane >> 3;
    float acc = 0.f, zacc = 0.f;
    int j = o0;
    for (; j + 4 <= o1; j += 4) {
        const int e0 = perm[j + 0];
        const int e1 = perm[j + 1];
        const int e2 = perm[j + 2];
        const int e3 = perm[j + 3];
        const int sv0 = src[e0];
        const int sv1 = src[e1];
        const int sv2 = src[e2];
        const int sv3 = src[e3];
        const float s0 = sg[(size_t)e0 * 8 + head];
        const float s1 = sg[(size_t)e1 * 8 + head];
        const float s2 = sg[(size_t)e2 * 8 + head];
        const float s3 = sg[(size_t)e3 * 8 + head];
        const float v0 = V[(size_t)sv0 * 64 + lane];
        const float v1 = V[(size_t)sv1 * 64 + lane];
        const float v2 = V[(size_t)sv2 * 64 + lane];
        const float v3 = V[(size_t)sv3 * 64 + lane];
        acc = fmaf(v0, s0, acc);
        acc = fmaf(v1, s1, acc);
        acc = fmaf(v2, s2, acc);
        acc = fmaf(v3, s3, acc);
        zacc += (s0 + s1) + (s2 + s3);
    }
    for (; j < o1; ++j) {
        const int ei = perm[j];
        const float s = sg[(size_t)ei * 8 + head];
        acc = fmaf(V[(size_t)src[ei] * 64 + lane], s, acc);
        zacc += s;
    }
    hout[(size_t)w * 64 + lane] = acc / (zacc + 1e-6f);
}

extern "C" void kernel_launch(void* const* d_in, const int* in_sizes, int n_in,
                              void* d_out, int out_size, void* d_ws, size_t ws_size,
                              hipStream_t stream)
{
    const float* h  = (const float*)d_in[0];
    const float* e  = (const float*)d_in[1];
    const float* Wq = (const float*)d_in[2];
    const float* bq = (const float*)d_in[3];
    const float* Wk = (const float*)d_in[4];
    const float* bk = (const float*)d_in[5];
    const float* Wv = (const float*)d_in[6];
    const float* bv = (const float*)d_in[7];
    const float* We = (const float*)d_in[8];
    const float* be = (const float*)d_in[9];
    const int* src  = (const int*)d_in[10];
    const int* dst  = (const int*)d_in[11];

    const int N = in_sizes[0] / 64;
    const int E = in_sizes[1] / 64;

    float* hout  = (float*)d_out;                    // [N*64]
    float* e_out = (float*)d_out + (size_t)N * 64;   // [E*64]

    // workspace layout
    char* ws = (char*)d_ws;
    float* Q = (float*)ws;                 ws += (size_t)N * 64 * sizeof(float);
    float* K = (float*)ws;                 ws += (size_t)N * 64 * sizeof(float);
    float* V = (float*)ws;                 ws += (size_t)N * 64 * sizeof(float);
    float* sg = (float*)ws;                ws += (size_t)E * 8 * sizeof(float);
    int* perm = (int*)ws;                  ws += (size_t)E * sizeof(int);
    int* counts  = (int*)ws;               ws += (size_t)N * sizeof(int);
    int* offsets = (int*)ws;               ws += (size_t)(N + 1) * sizeof(int);
    int* cursor  = (int*)ws;               ws += (size_t)N * sizeof(int);
    int* bsum    = (int*)ws;               ws += 64 * sizeof(int);

    hipMemsetAsync(counts, 0, (size_t)N * sizeof(int), stream);

    // 1) Q,K,V projections
    proj_kernel<<<dim3(512, 3), dim3(256), 0, stream>>>(
        h, Wq, bq, Wk, bk, Wv, bv, Q, K, V, N);

    // 2) dst histogram
    hist_kernel<<<dim3(2048), dim3(256), 0, stream>>>(dst, counts, E);

    // 3) exclusive scan -> offsets, cursor (multi-block, 3 kernels)
    const int nb = (N + 1023) / 1024;
    scan1_kernel<<<dim3(nb), dim3(1024), 0, stream>>>(counts, offsets, bsum, N);
    scan2_kernel<<<dim3(1), dim3(64), 0, stream>>>(bsum, nb);
    scan3_kernel<<<dim3(nb), dim3(1024), 0, stream>>>(offsets, cursor, bsum, N, E);

    // 4) permutation build (lean atomic kernel, huge TLP)
    slot_kernel<<<dim3(2048), dim3(256), 0, stream>>>(dst, cursor, perm, E);

    // 5) edge pass: MFMA, no atomics, 1 tile per wave
    const int ntiles = (E + 63) >> 6;
    const int eblocks = (ntiles + 3) / 4;           // 6250
    edge_kernel<<<dim3(eblocks), dim3(256), 0, stream>>>(
        e, We, be, src, dst, Q, K, e_out, sg, E);

    // 6) aggregate per node (one wave each)
    const int ablocks = (N * 64 + 255) / 256;
    aggregate_kernel<<<dim3(ablocks), dim3(256), 0, stream>>>(
        offsets, perm, src, sg, V, hout, N);
}

// Round 11
// 609.237 us; speedup vs baseline: 1.1097x; 1.1097x over previous
//
#include <hip/hip_runtime.h>

// Graph-transformer MHA layer. N=50000, E=1600000, IN_DIM=64, H=8, D=8.
// Outputs: h_out [N*64] then e_out [E*64], fp32, concatenated in d_out.
//
// R11: permutation randomness moved to fire-and-forget scatters.
//  - slot_kernel: rank[i] = atomicAdd(cursor[dst[i]],1)  (coalesced write)
//  - edge_kernel: reads rank[eid] (coalesced), scatter-writes gates/src to
//    s_sorted[rank]/src_sorted[rank] (no return dependency; L3 absorbs RFO).
//    K/Q rows preloaded per eh BEFORE the MFMA block (deep load window).
//  - aggregate_kernel: R9's coalesced form (s_sorted/src_sorted sequential).
// (R10 lesson: perm randomness in the serial per-node aggregate loop cost
//  +170us; random side must live in a TLP-rich fire-and-forget kernel.)

using short8 = __attribute__((ext_vector_type(8))) short;
using f32x16 = __attribute__((ext_vector_type(16))) float;

__device__ __forceinline__ short f2bf(float f) {
    unsigned u = __builtin_bit_cast(unsigned, f);
    u += 0x7FFF + ((u >> 16) & 1);          // RNE to bf16
    return (short)(u >> 16);
}

// ---------------- node projection ----------------
__global__ __launch_bounds__(256)
void proj_kernel(const float* __restrict__ hsrc,
                 const float* __restrict__ Wq, const float* __restrict__ bq,
                 const float* __restrict__ Wk, const float* __restrict__ bk,
                 const float* __restrict__ Wv, const float* __restrict__ bv,
                 float* __restrict__ Q, float* __restrict__ K, float* __restrict__ V,
                 int n)
{
    const float* W;
    const float* b;
    float* out;
    if (blockIdx.y == 0)      { W = Wq; b = bq; out = Q; }
    else if (blockIdx.y == 1) { W = Wk; b = bk; out = K; }
    else                      { W = Wv; b = bv; out = V; }

    const int t    = threadIdx.x;
    const int lane = t & 63;
    const int w    = t >> 6;

    float wcol[64];
#pragma unroll
    for (int k = 0; k < 64; ++k) wcol[k] = W[k * 64 + lane];
    const float bias = b[lane];

    __shared__ float4 sh[16][16];
    const float4* __restrict__ h4 = (const float4*)hsrc;

    const int ngroups = (n + 15) >> 4;
    for (int g = blockIdx.x; g < ngroups; g += gridDim.x) {
        const int base = g << 4;
        {
            const int rs = t >> 4, c4 = t & 15;
            float4 v = make_float4(0.f, 0.f, 0.f, 0.f);
            if (base + rs < n) v = h4[(size_t)(base + rs) * 16 + c4];
            __syncthreads();
            sh[rs][c4] = v;
            __syncthreads();
        }
        float acc0 = bias, acc1 = bias, acc2 = bias, acc3 = bias;
#pragma unroll
        for (int k4 = 0; k4 < 16; ++k4) {
            const float w0 = wcol[k4 * 4 + 0], w1 = wcol[k4 * 4 + 1];
            const float w2 = wcol[k4 * 4 + 2], w3 = wcol[k4 * 4 + 3];
            const float4 a = sh[w * 4 + 0][k4];
            const float4 bb = sh[w * 4 + 1][k4];
            const float4 c = sh[w * 4 + 2][k4];
            const float4 d = sh[w * 4 + 3][k4];
            acc0 = fmaf(a.w,  w3, fmaf(a.z,  w2, fmaf(a.y,  w1, fmaf(a.x,  w0, acc0))));
            acc1 = fmaf(bb.w, w3, fmaf(bb.z, w2, fmaf(bb.y, w1, fmaf(bb.x, w0, acc1))));
            acc2 = fmaf(c.w,  w3, fmaf(c.z,  w2, fmaf(c.y,  w1, fmaf(c.x,  w0, acc2))));
            acc3 = fmaf(d.w,  w3, fmaf(d.z,  w2, fmaf(d.y,  w1, fmaf(d.x,  w0, acc3))));
        }
        const int n0 = base + w * 4;
        if (n0 + 0 < n) out[(size_t)(n0 + 0) * 64 + lane] = acc0;
        if (n0 + 1 < n) out[(size_t)(n0 + 1) * 64 + lane] = acc1;
        if (n0 + 2 < n) out[(size_t)(n0 + 2) * 64 + lane] = acc2;
        if (n0 + 3 < n) out[(size_t)(n0 + 3) * 64 + lane] = acc3;
    }
}

// ---------------- dst histogram ----------------
__global__ __launch_bounds__(256)
void hist_kernel(const int* __restrict__ dst, int* __restrict__ counts, int E)
{
    int i = blockIdx.x * 256 + threadIdx.x;
    const int stride = gridDim.x * 256;
    for (; i < E; i += stride) atomicAdd(&counts[dst[i]], 1);
}

// ---------------- multi-block exclusive scan (3 kernels) ----------------
__global__ __launch_bounds__(1024)
void scan1_kernel(const int* __restrict__ counts, int* __restrict__ offsets,
                  int* __restrict__ bsum, int n)
{
    const int t = threadIdx.x;
    const int lane = t & 63;
    const int w = t >> 6;
    __shared__ int wsum[16];
    const int i = blockIdx.x * 1024 + t;
    const int v = (i < n) ? counts[i] : 0;
    int x = v;
#pragma unroll
    for (int d = 1; d < 64; d <<= 1) {
        int y = __shfl_up(x, d);
        if (lane >= d) x += y;
    }
    if (lane == 63) wsum[w] = x;
    __syncthreads();
    if (w == 0 && lane < 16) {
        int s = wsum[lane];
#pragma unroll
        for (int d = 1; d < 16; d <<= 1) {
            int y = __shfl_up(s, d);
            if (lane >= d) s += y;
        }
        wsum[lane] = s;
    }
    __syncthreads();
    const int excl = ((w == 0) ? 0 : wsum[w - 1]) + (x - v);
    if (i < n) offsets[i] = excl;
    if (t == 1023) bsum[blockIdx.x] = excl + v;
}

__global__ __launch_bounds__(64)
void scan2_kernel(int* __restrict__ bsum, int nb)
{
    const int lane = threadIdx.x;
    const int v = (lane < nb) ? bsum[lane] : 0;
    int x = v;
#pragma unroll
    for (int d = 1; d < 64; d <<= 1) {
        int y = __shfl_up(x, d);
        if (lane >= d) x += y;
    }
    if (lane < nb) bsum[lane] = x - v;   // exclusive
}

__global__ __launch_bounds__(1024)
void scan3_kernel(int* __restrict__ offsets, int* __restrict__ cursor,
                  const int* __restrict__ bsum, int n, int E)
{
    const int i = blockIdx.x * 1024 + threadIdx.x;
    if (i < n) {
        const int off = offsets[i] + bsum[blockIdx.x];
        offsets[i] = off;
        cursor[i] = off;
    }
    if (blockIdx.x == 0 && threadIdx.x == 0) offsets[n] = E;
}

// ---------------- slot kernel: per-edge sorted rank (coalesced write) ----------------
__global__ __launch_bounds__(256)
void slot_kernel(const int* __restrict__ dst, int* __restrict__ cursor,
                 int* __restrict__ rank, int E)
{
    int i = blockIdx.x * 256 + threadIdx.x;
    const int stride = gridDim.x * 256;
    for (; i < E; i += stride) {
        rank[i] = atomicAdd(&cursor[dst[i]], 1);
    }
}

// ---------------- edge kernel v11: MFMA, rank-scattered gates ----------------
__global__ __launch_bounds__(256)
void edge_kernel(const float* __restrict__ e,
                 const float* __restrict__ We, const float* __restrict__ be,
                 const int* __restrict__ src, const int* __restrict__ dst,
                 const float* __restrict__ Q, const float* __restrict__ K,
                 float* __restrict__ e_out,
                 float* __restrict__ s_sorted, int* __restrict__ src_sorted,
                 const int* __restrict__ rank, int E)
{
    __shared__ float4 tile4[4][32 * 8];             // 4KB per wave, XOR-swizzled
    const int t    = threadIdx.x;
    const int lane = t & 63;
    const int wu   = __builtin_amdgcn_readfirstlane(t >> 6);
    const int lid  = lane & 31;
    const int hi   = lane >> 5;
    float4* const myT4 = tile4[wu];
    const float inv = 0.35355339059327373f;         // 1/sqrt(8)

    // A fragments (We^T), loaded once per wave. A[jh][ks] elem (4g+i) holds
    // We[k = 16ks + 8g + 4hi + i][j = 32jh + lid].
    short8 Afr[2][4];
#pragma unroll
    for (int jh = 0; jh < 2; ++jh)
#pragma unroll
        for (int ks = 0; ks < 4; ++ks)
#pragma unroll
            for (int g = 0; g < 2; ++g)
#pragma unroll
                for (int i = 0; i < 4; ++i)
                    Afr[jh][ks][4 * g + i] =
                        f2bf(We[(16 * ks + 8 * g + 4 * hi + i) * 64 + 32 * jh + lid]);

    const int ntiles = (E + 63) >> 6;
    for (int tb = blockIdx.x * 4 + wu; tb < ntiles; tb += gridDim.x * 4) {
        const int base = tb << 6;

#pragma unroll
        for (int eh = 0; eh < 2; ++eh) {
            const int erow_i = base + eh * 32 + lid;
            const int erc = erow_i < E ? erow_i : (E - 1);
            const int se = src[erc];
            const int de = dst[erc];
            const int rk = rank[erc];

            // e row loads issued first
            const float* er = e + (size_t)erc * 64 + 4 * hi;
            float4 p[8];
#pragma unroll
            for (int q = 0; q < 8; ++q)
                p[q] = *(const float4*)(er + 16 * (q >> 1) + 8 * (q & 1));

            // K/Q rows for BOTH jh preloaded (deep load window under cvt+MFMA)
            const float* kb = K + (size_t)se * 64 + 4 * hi;
            const float* qb = Q + (size_t)de * 64 + 4 * hi;
            float4 kv[2][4], qv[2][4];
#pragma unroll
            for (int jh = 0; jh < 2; ++jh)
#pragma unroll
                for (int hd = 0; hd < 4; ++hd) {
                    kv[jh][hd] = *(const float4*)(kb + 32 * jh + 8 * hd);
                    qv[jh][hd] = *(const float4*)(qb + 32 * jh + 8 * hd);
                }

            // cvt B fragments: elem (4g+i) = e[row][k = 16ks + 8g + 4hi + i]
            short8 Bfr[4];
#pragma unroll
            for (int ks = 0; ks < 4; ++ks) {
                const float4 p0 = p[2 * ks], p1 = p[2 * ks + 1];
                Bfr[ks][0] = f2bf(p0.x); Bfr[ks][1] = f2bf(p0.y);
                Bfr[ks][2] = f2bf(p0.z); Bfr[ks][3] = f2bf(p0.w);
                Bfr[ks][4] = f2bf(p1.x); Bfr[ks][5] = f2bf(p1.y);
                Bfr[ks][6] = f2bf(p1.z); Bfr[ks][7] = f2bf(p1.w);
            }

            float gate[8];
#pragma unroll
            for (int jh = 0; jh < 2; ++jh) {
                f32x16 D = {};
#pragma unroll
                for (int ks = 0; ks < 4; ++ks)
                    D = __builtin_amdgcn_mfma_f32_32x32x16_bf16(
                            Afr[jh][ks], Bfr[ks], D, 0, 0, 0);

                // previous phase's LDS reads must be done before overwrite
                asm volatile("s_waitcnt lgkmcnt(0)" ::: "memory");

                // epilogue: preloaded kv/qv; stage + head sums
#pragma unroll
                for (int hd = 0; hd < 4; ++hd) {
                    const float4 bev = *(const float4*)(be + 32 * jh + 8 * hd + 4 * hi);
                    const float4 k4 = kv[jh][hd];
                    const float4 q4 = qv[jh][hd];
                    // reg r = 4*hd + i  ->  j_local(within jh) = 8*hd + 4*hi + i
                    const float s0 = k4.x * q4.x * inv * (D[4 * hd + 0] + bev.x);
                    const float s1 = k4.y * q4.y * inv * (D[4 * hd + 1] + bev.y);
                    const float s2 = k4.z * q4.z * inv * (D[4 * hd + 2] + bev.z);
                    const float s3 = k4.w * q4.w * inv * (D[4 * hd + 3] + bev.w);
                    const int c4 = (2 * hd + hi) ^ (lid & 7);       // XOR swizzle
                    myT4[lid * 8 + c4] = make_float4(s0, s1, s2, s3);
                    float pp = (s0 + s1) + (s2 + s3);
                    const float full = pp + __shfl_xor(pp, 32);     // head = 4jh+hd
                    gate[jh * 4 + hd] = expf(fminf(fmaxf(full, -5.f), 5.f));
                }

                // readout: 4 x 64-lane dwordx4 stores of 128B half-rows
                const int r8 = lane >> 3, m = lane & 7;
#pragma unroll
                for (int it = 0; it < 4; ++it) {
                    const int row = it * 8 + r8;                    // edge row 0..31
                    const int edge2 = base + eh * 32 + row;
                    const float4 v = myT4[row * 8 + (m ^ (row & 7))];
                    if (edge2 < E)
                        *((float4*)e_out + (size_t)edge2 * 16 + jh * 8 + m) = v;
                }
            }

            // rank-scattered gate + src writes (fire-and-forget, L3 absorbs RFO)
            if (erow_i < E) {
                const float4 g = (hi == 0)
                    ? make_float4(gate[0], gate[1], gate[2], gate[3])
                    : make_float4(gate[4], gate[5], gate[6], gate[7]);
                *(float4*)(s_sorted + (size_t)rk * 8 + hi * 4) = g;
                if (hi == 0) src_sorted[rk] = se;
            }
        }
    }
}

// ---------------- aggregation: one wave per node, coalesced sorted reads ----------------
__global__ __launch_bounds__(256)
void aggregate_kernel(const int* __restrict__ offsets,
                      const int* __restrict__ src_sorted,
                      const float* __restrict__ s_sorted,
                      const float* __restrict__ V,
                      float* __restrict__ hout, int n)
{
    const int w = (blockIdx.x * 256 + threadIdx.x) >> 6;
    const int lane = threadIdx.x & 63;
    if (w >= n) return;
    const int o0 = offsets[w], o1 = offsets[w + 1];
    const int head = lane >> 3;
    float acc = 0.f, zacc = 0.f;
    int j = o0;
    for (; j + 4 <= o1; j += 4) {
        const int sv0 = src_sorted[j + 0];
        const int sv1 = src_sorted[j + 1];
        const int sv2 = src_sorted[j + 2];
        const int sv3 = src_sorted[j + 3];
        const float s0 = s_sorted[(size_t)(j + 0) * 8 + head];
        const float s1 = s_sorted[(size_t)(j + 1) * 8 + head];
        const float s2 = s_sorted[(size_t)(j + 2) * 8 + head];
        const float s3 = s_sorted[(size_t)(j + 3) * 8 + head];
        const float v0 = V[(size_t)sv0 * 64 + lane];
        const float v1 = V[(size_t)sv1 * 64 + lane];
        const float v2 = V[(size_t)sv2 * 64 + lane];
        const float v3 = V[(size_t)sv3 * 64 + lane];
        acc = fmaf(v0, s0, acc);
        acc = fmaf(v1, s1, acc);
        acc = fmaf(v2, s2, acc);
        acc = fmaf(v3, s3, acc);
        zacc += (s0 + s1) + (s2 + s3);
    }
    for (; j < o1; ++j) {
        const int sv = src_sorted[j];
        const float s = s_sorted[(size_t)j * 8 + head];
        acc = fmaf(V[(size_t)sv * 64 + lane], s, acc);
        zacc += s;
    }
    hout[(size_t)w * 64 + lane] = acc / (zacc + 1e-6f);
}

extern "C" void kernel_launch(void* const* d_in, const int* in_sizes, int n_in,
                              void* d_out, int out_size, void* d_ws, size_t ws_size,
                              hipStream_t stream)
{
    const float* h  = (const float*)d_in[0];
    const float* e  = (const float*)d_in[1];
    const float* Wq = (const float*)d_in[2];
    const float* bq = (const float*)d_in[3];
    const float* Wk = (const float*)d_in[4];
    const float* bk = (const float*)d_in[5];
    const float* Wv = (const float*)d_in[6];
    const float* bv = (const float*)d_in[7];
    const float* We = (const float*)d_in[8];
    const float* be = (const float*)d_in[9];
    const int* src  = (const int*)d_in[10];
    const int* dst  = (const int*)d_in[11];

    const int N = in_sizes[0] / 64;
    const int E = in_sizes[1] / 64;

    float* hout  = (float*)d_out;                    // [N*64]
    float* e_out = (float*)d_out + (size_t)N * 64;   // [E*64]

    // workspace layout
    char* ws = (char*)d_ws;
    float* Q = (float*)ws;                 ws += (size_t)N * 64 * sizeof(float);
    float* K = (float*)ws;                 ws += (size_t)N * 64 * sizeof(float);
    float* V = (float*)ws;                 ws += (size_t)N * 64 * sizeof(float);
    float* s_sorted = (float*)ws;          ws += (size_t)E * 8 * sizeof(float);
    int* src_sorted = (int*)ws;            ws += (size_t)E * sizeof(int);
    int* rank = (int*)ws;                  ws += (size_t)E * sizeof(int);
    int* counts  = (int*)ws;               ws += (size_t)N * sizeof(int);
    int* offsets = (int*)ws;               ws += (size_t)(N + 1) * sizeof(int);
    int* cursor  = (int*)ws;               ws += (size_t)N * sizeof(int);
    int* bsum    = (int*)ws;               ws += 64 * sizeof(int);

    hipMemsetAsync(counts, 0, (size_t)N * sizeof(int), stream);

    // 1) Q,K,V projections
    proj_kernel<<<dim3(512, 3), dim3(256), 0, stream>>>(
        h, Wq, bq, Wk, bk, Wv, bv, Q, K, V, N);

    // 2) dst histogram
    hist_kernel<<<dim3(2048), dim3(256), 0, stream>>>(dst, counts, E);

    // 3) exclusive scan -> offsets, cursor (multi-block, 3 kernels)
    const int nb = (N + 1023) / 1024;
    scan1_kernel<<<dim3(nb), dim3(1024), 0, stream>>>(counts, offsets, bsum, N);
    scan2_kernel<<<dim3(1), dim3(64), 0, stream>>>(bsum, nb);
    scan3_kernel<<<dim3(nb), dim3(1024), 0, stream>>>(offsets, cursor, bsum, N, E);

    // 4) rank build (lean atomic kernel, coalesced rank write)
    slot_kernel<<<dim3(2048), dim3(256), 0, stream>>>(dst, cursor, rank, E);

    // 5) edge pass: MFMA, rank-scattered gates
    const int ntiles = (E + 63) >> 6;
    const int eblocks = (ntiles + 3) / 4;           // 6250
    edge_kernel<<<dim3(eblocks), dim3(256), 0, stream>>>(
        e, We, be, src, dst, Q, K, e_out, s_sorted, src_sorted, rank, E);

    // 6) aggregate per node (one wave each)
    const int ablocks = (N * 64 + 255) / 256;
    aggregate_kernel<<<dim3(ablocks), dim3(256), 0, stream>>>(
        offsets, src_sorted, s_sorted, V, hout, N);
}

// Round 12
// 569.944 us; speedup vs baseline: 1.1862x; 1.0689x over previous
//
#include <hip/hip_runtime.h>

// Graph-transformer MHA layer. N=50000, E=1600000, IN_DIM=64, H=8, D=8.
// Outputs: h_out [N*64] then e_out [E*64], fp32, concatenated in d_out.
//
// R12:
//  - rank_kernel merges hist+slot: rank[i] = atomicAdd(counts[dst[i]],1) in
//    the SAME pass that builds the histogram (one dst traversal, one atomic
//    pass instead of two). Final slot = offsets[dst] + rank, computed in the
//    edge kernel (offsets is a 200KB L2-resident gather feeding only a store
//    address - no compute dependency).
//  - edge kernel: R10's low-VGPR JIT-epilogue structure (best measured) +
//    fire-and-forget rank-scatter of gates/src.
//  - aggregate: coalesced sorted reads (R11 form).

using short8 = __attribute__((ext_vector_type(8))) short;
using f32x16 = __attribute__((ext_vector_type(16))) float;

__device__ __forceinline__ short f2bf(float f) {
    unsigned u = __builtin_bit_cast(unsigned, f);
    u += 0x7FFF + ((u >> 16) & 1);          // RNE to bf16
    return (short)(u >> 16);
}

// ---------------- node projection ----------------
__global__ __launch_bounds__(256)
void proj_kernel(const float* __restrict__ hsrc,
                 const float* __restrict__ Wq, const float* __restrict__ bq,
                 const float* __restrict__ Wk, const float* __restrict__ bk,
                 const float* __restrict__ Wv, const float* __restrict__ bv,
                 float* __restrict__ Q, float* __restrict__ K, float* __restrict__ V,
                 int n)
{
    const float* W;
    const float* b;
    float* out;
    if (blockIdx.y == 0)      { W = Wq; b = bq; out = Q; }
    else if (blockIdx.y == 1) { W = Wk; b = bk; out = K; }
    else                      { W = Wv; b = bv; out = V; }

    const int t    = threadIdx.x;
    const int lane = t & 63;
    const int w    = t >> 6;

    float wcol[64];
#pragma unroll
    for (int k = 0; k < 64; ++k) wcol[k] = W[k * 64 + lane];
    const float bias = b[lane];

    __shared__ float4 sh[16][16];
    const float4* __restrict__ h4 = (const float4*)hsrc;

    const int ngroups = (n + 15) >> 4;
    for (int g = blockIdx.x; g < ngroups; g += gridDim.x) {
        const int base = g << 4;
        {
            const int rs = t >> 4, c4 = t & 15;
            float4 v = make_float4(0.f, 0.f, 0.f, 0.f);
            if (base + rs < n) v = h4[(size_t)(base + rs) * 16 + c4];
            __syncthreads();
            sh[rs][c4] = v;
            __syncthreads();
        }
        float acc0 = bias, acc1 = bias, acc2 = bias, acc3 = bias;
#pragma unroll
        for (int k4 = 0; k4 < 16; ++k4) {
            const float w0 = wcol[k4 * 4 + 0], w1 = wcol[k4 * 4 + 1];
            const float w2 = wcol[k4 * 4 + 2], w3 = wcol[k4 * 4 + 3];
            const float4 a = sh[w * 4 + 0][k4];
            const float4 bb = sh[w * 4 + 1][k4];
            const float4 c = sh[w * 4 + 2][k4];
            const float4 d = sh[w * 4 + 3][k4];
            acc0 = fmaf(a.w,  w3, fmaf(a.z,  w2, fmaf(a.y,  w1, fmaf(a.x,  w0, acc0))));
            acc1 = fmaf(bb.w, w3, fmaf(bb.z, w2, fmaf(bb.y, w1, fmaf(bb.x, w0, acc1))));
            acc2 = fmaf(c.w,  w3, fmaf(c.z,  w2, fmaf(c.y,  w1, fmaf(c.x,  w0, acc2))));
            acc3 = fmaf(d.w,  w3, fmaf(d.z,  w2, fmaf(d.y,  w1, fmaf(d.x,  w0, acc3))));
        }
        const int n0 = base + w * 4;
        if (n0 + 0 < n) out[(size_t)(n0 + 0) * 64 + lane] = acc0;
        if (n0 + 1 < n) out[(size_t)(n0 + 1) * 64 + lane] = acc1;
        if (n0 + 2 < n) out[(size_t)(n0 + 2) * 64 + lane] = acc2;
        if (n0 + 3 < n) out[(size_t)(n0 + 3) * 64 + lane] = acc3;
    }
}

// ---------------- rank kernel: histogram + within-segment rank in ONE pass ----------------
__global__ __launch_bounds__(256)
void rank_kernel(const int* __restrict__ dst, int* __restrict__ counts,
                 int* __restrict__ rank, int E)
{
    int i = blockIdx.x * 256 + threadIdx.x;
    const int stride = gridDim.x * 256;
    for (; i < E; i += stride) {
        rank[i] = atomicAdd(&counts[dst[i]], 1);
    }
}

// ---------------- multi-block exclusive scan (3 kernels) ----------------
__global__ __launch_bounds__(1024)
void scan1_kernel(const int* __restrict__ counts, int* __restrict__ offsets,
                  int* __restrict__ bsum, int n)
{
    const int t = threadIdx.x;
    const int lane = t & 63;
    const int w = t >> 6;
    __shared__ int wsum[16];
    const int i = blockIdx.x * 1024 + t;
    const int v = (i < n) ? counts[i] : 0;
    int x = v;
#pragma unroll
    for (int d = 1; d < 64; d <<= 1) {
        int y = __shfl_up(x, d);
        if (lane >= d) x += y;
    }
    if (lane == 63) wsum[w] = x;
    __syncthreads();
    if (w == 0 && lane < 16) {
        int s = wsum[lane];
#pragma unroll
        for (int d = 1; d < 16; d <<= 1) {
            int y = __shfl_up(s, d);
            if (lane >= d) s += y;
        }
        wsum[lane] = s;
    }
    __syncthreads();
    const int excl = ((w == 0) ? 0 : wsum[w - 1]) + (x - v);
    if (i < n) offsets[i] = excl;
    if (t == 1023) bsum[blockIdx.x] = excl + v;
}

__global__ __launch_bounds__(64)
void scan2_kernel(int* __restrict__ bsum, int nb)
{
    const int lane = threadIdx.x;
    const int v = (lane < nb) ? bsum[lane] : 0;
    int x = v;
#pragma unroll
    for (int d = 1; d < 64; d <<= 1) {
        int y = __shfl_up(x, d);
        if (lane >= d) x += y;
    }
    if (lane < nb) bsum[lane] = x - v;   // exclusive
}

__global__ __launch_bounds__(1024)
void scan3_kernel(int* __restrict__ offsets, const int* __restrict__ bsum,
                  int n, int E)
{
    const int i = blockIdx.x * 1024 + threadIdx.x;
    if (i < n) offsets[i] += bsum[blockIdx.x];
    if (blockIdx.x == 0 && threadIdx.x == 0) offsets[n] = E;
}

// ---------------- edge kernel v12: MFMA, JIT epilogue, rank-scattered gates ----------------
__global__ __launch_bounds__(256)
void edge_kernel(const float* __restrict__ e,
                 const float* __restrict__ We, const float* __restrict__ be,
                 const int* __restrict__ src, const int* __restrict__ dst,
                 const float* __restrict__ Q, const float* __restrict__ K,
                 float* __restrict__ e_out,
                 float* __restrict__ s_sorted, int* __restrict__ src_sorted,
                 const int* __restrict__ rank, const int* __restrict__ offs,
                 int E)
{
    __shared__ float4 tile4[4][32 * 8];             // 4KB per wave, XOR-swizzled
    const int t    = threadIdx.x;
    const int lane = t & 63;
    const int wu   = __builtin_amdgcn_readfirstlane(t >> 6);
    const int lid  = lane & 31;
    const int hi   = lane >> 5;
    float4* const myT4 = tile4[wu];
    const float inv = 0.35355339059327373f;         // 1/sqrt(8)

    // A fragments (We^T), loaded once per wave. A[jh][ks] elem (4g+i) holds
    // We[k = 16ks + 8g + 4hi + i][j = 32jh + lid].
    short8 Afr[2][4];
#pragma unroll
    for (int jh = 0; jh < 2; ++jh)
#pragma unroll
        for (int ks = 0; ks < 4; ++ks)
#pragma unroll
            for (int g = 0; g < 2; ++g)
#pragma unroll
                for (int i = 0; i < 4; ++i)
                    Afr[jh][ks][4 * g + i] =
                        f2bf(We[(16 * ks + 8 * g + 4 * hi + i) * 64 + 32 * jh + lid]);

    const int ntiles = (E + 63) >> 6;
    for (int tb = blockIdx.x * 4 + wu; tb < ntiles; tb += gridDim.x * 4) {
        const int base = tb << 6;

#pragma unroll
        for (int eh = 0; eh < 2; ++eh) {
            const int erow_i = base + eh * 32 + lid;
            const int erc = erow_i < E ? erow_i : (E - 1);
            const int se = src[erc];
            const int de = dst[erc];
            // sorted slot: offsets gather feeds only the store address
            const int rk = offs[de] + rank[erc];

            // B fragments: elem (4g+i) = e[row][k = 16ks + 8g + 4hi + i]
            const float* er = e + (size_t)erc * 64 + 4 * hi;
            short8 Bfr[4];
#pragma unroll
            for (int ks = 0; ks < 4; ++ks) {
                const float4 p0 = *(const float4*)(er + 16 * ks);
                const float4 p1 = *(const float4*)(er + 16 * ks + 8);
                Bfr[ks][0] = f2bf(p0.x); Bfr[ks][1] = f2bf(p0.y);
                Bfr[ks][2] = f2bf(p0.z); Bfr[ks][3] = f2bf(p0.w);
                Bfr[ks][4] = f2bf(p1.x); Bfr[ks][5] = f2bf(p1.y);
                Bfr[ks][6] = f2bf(p1.z); Bfr[ks][7] = f2bf(p1.w);
            }

            float gate[8];
#pragma unroll
            for (int jh = 0; jh < 2; ++jh) {
                f32x16 D = {};
#pragma unroll
                for (int ks = 0; ks < 4; ++ks)
                    D = __builtin_amdgcn_mfma_f32_32x32x16_bf16(
                            Afr[jh][ks], Bfr[ks], D, 0, 0, 0);

                // previous phase's LDS reads must be done before overwrite
                asm volatile("s_waitcnt lgkmcnt(0)" ::: "memory");

                // epilogue: JIT kv/qv/bev loads per hd; stage + head sums
                const float* kb = K + (size_t)se * 64 + 32 * jh + 4 * hi;
                const float* qb = Q + (size_t)de * 64 + 32 * jh + 4 * hi;
#pragma unroll
                for (int hd = 0; hd < 4; ++hd) {
                    const float4 kv  = *(const float4*)(kb + 8 * hd);
                    const float4 qv  = *(const float4*)(qb + 8 * hd);
                    const float4 bev = *(const float4*)(be + 32 * jh + 8 * hd + 4 * hi);
                    // reg r = 4*hd + i  ->  j_local(within jh) = 8*hd + 4*hi + i
                    const float s0 = kv.x * qv.x * inv * (D[4 * hd + 0] + bev.x);
                    const float s1 = kv.y * qv.y * inv * (D[4 * hd + 1] + bev.y);
                    const float s2 = kv.z * qv.z * inv * (D[4 * hd + 2] + bev.z);
                    const float s3 = kv.w * qv.w * inv * (D[4 * hd + 3] + bev.w);
                    const int c4 = (2 * hd + hi) ^ (lid & 7);       // XOR swizzle
                    myT4[lid * 8 + c4] = make_float4(s0, s1, s2, s3);
                    float p = (s0 + s1) + (s2 + s3);
                    const float full = p + __shfl_xor(p, 32);       // head = 4jh+hd
                    gate[jh * 4 + hd] = expf(fminf(fmaxf(full, -5.f), 5.f));
                }

                // readout: 4 x 64-lane dwordx4 stores of 128B half-rows
                const int r8 = lane >> 3, m = lane & 7;
#pragma unroll
                for (int it = 0; it < 4; ++it) {
                    const int row = it * 8 + r8;                    // edge row 0..31
                    const int edge2 = base + eh * 32 + row;
                    const float4 v = myT4[row * 8 + (m ^ (row & 7))];
                    if (edge2 < E)
                        *((float4*)e_out + (size_t)edge2 * 16 + jh * 8 + m) = v;
                }
            }

            // rank-scattered gate + src writes (fire-and-forget, L3 absorbs RFO)
            if (erow_i < E) {
                const float4 g = (hi == 0)
                    ? make_float4(gate[0], gate[1], gate[2], gate[3])
                    : make_float4(gate[4], gate[5], gate[6], gate[7]);
                *(float4*)(s_sorted + (size_t)rk * 8 + hi * 4) = g;
                if (hi == 0) src_sorted[rk] = se;
            }
        }
    }
}

// ---------------- aggregation: one wave per node, coalesced sorted reads ----------------
__global__ __launch_bounds__(256)
void aggregate_kernel(const int* __restrict__ offsets,
                      const int* __restrict__ src_sorted,
                      const float* __restrict__ s_sorted,
                      const float* __restrict__ V,
                      float* __restrict__ hout, int n)
{
    const int w = (blockIdx.x * 256 + threadIdx.x) >> 6;
    const int lane = threadIdx.x & 63;
    if (w >= n) return;
    const int o0 = offsets[w], o1 = offsets[w + 1];
    const int head = lane >> 3;
    float acc = 0.f, zacc = 0.f;
    int j = o0;
    for (; j + 4 <= o1; j += 4) {
        const int sv0 = src_sorted[j + 0];
        const int sv1 = src_sorted[j + 1];
        const int sv2 = src_sorted[j + 2];
        const int sv3 = src_sorted[j + 3];
        const float s0 = s_sorted[(size_t)(j + 0) * 8 + head];
        const float s1 = s_sorted[(size_t)(j + 1) * 8 + head];
        const float s2 = s_sorted[(size_t)(j + 2) * 8 + head];
        const float s3 = s_sorted[(size_t)(j + 3) * 8 + head];
        const float v0 = V[(size_t)sv0 * 64 + lane];
        const float v1 = V[(size_t)sv1 * 64 + lane];
        const float v2 = V[(size_t)sv2 * 64 + lane];
        const float v3 = V[(size_t)sv3 * 64 + lane];
        acc = fmaf(v0, s0, acc);
        acc = fmaf(v1, s1, acc);
        acc = fmaf(v2, s2, acc);
        acc = fmaf(v3, s3, acc);
        zacc += (s0 + s1) + (s2 + s3);
    }
    for (; j < o1; ++j) {
        const int sv = src_sorted[j];
        const float s = s_sorted[(size_t)j * 8 + head];
        acc = fmaf(V[(size_t)sv * 64 + lane], s, acc);
        zacc += s;
    }
    hout[(size_t)w * 64 + lane] = acc / (zacc + 1e-6f);
}

extern "C" void kernel_launch(void* const* d_in, const int* in_sizes, int n_in,
                              void* d_out, int out_size, void* d_ws, size_t ws_size,
                              hipStream_t stream)
{
    const float* h  = (const float*)d_in[0];
    const float* e  = (const float*)d_in[1];
    const float* Wq = (const float*)d_in[2];
    const float* bq = (const float*)d_in[3];
    const float* Wk = (const float*)d_in[4];
    const float* bk = (const float*)d_in[5];
    const float* Wv = (const float*)d_in[6];
    const float* bv = (const float*)d_in[7];
    const float* We = (const float*)d_in[8];
    const float* be = (const float*)d_in[9];
    const int* src  = (const int*)d_in[10];
    const int* dst  = (const int*)d_in[11];

    const int N = in_sizes[0] / 64;
    const int E = in_sizes[1] / 64;

    float* hout  = (float*)d_out;                    // [N*64]
    float* e_out = (float*)d_out + (size_t)N * 64;   // [E*64]

    // workspace layout
    char* ws = (char*)d_ws;
    float* Q = (float*)ws;                 ws += (size_t)N * 64 * sizeof(float);
    float* K = (float*)ws;                 ws += (size_t)N * 64 * sizeof(float);
    float* V = (float*)ws;                 ws += (size_t)N * 64 * sizeof(float);
    float* s_sorted = (float*)ws;          ws += (size_t)E * 8 * sizeof(float);
    int* src_sorted = (int*)ws;            ws += (size_t)E * sizeof(int);
    int* rank = (int*)ws;                  ws += (size_t)E * sizeof(int);
    int* counts  = (int*)ws;               ws += (size_t)N * sizeof(int);
    int* offsets = (int*)ws;               ws += (size_t)(N + 1) * sizeof(int);
    int* bsum    = (int*)ws;               ws += 64 * sizeof(int);

    hipMemsetAsync(counts, 0, (size_t)N * sizeof(int), stream);

    // 1) Q,K,V projections
    proj_kernel<<<dim3(512, 3), dim3(256), 0, stream>>>(
        h, Wq, bq, Wk, bk, Wv, bv, Q, K, V, N);

    // 2) histogram + rank in one pass
    rank_kernel<<<dim3(2048), dim3(256), 0, stream>>>(dst, counts, rank, E);

    // 3) exclusive scan -> offsets (multi-block, 3 kernels)
    const int nb = (N + 1023) / 1024;
    scan1_kernel<<<dim3(nb), dim3(1024), 0, stream>>>(counts, offsets, bsum, N);
    scan2_kernel<<<dim3(1), dim3(64), 0, stream>>>(bsum, nb);
    scan3_kernel<<<dim3(nb), dim3(1024), 0, stream>>>(offsets, bsum, N, E);

    // 4) edge pass: MFMA, rank-scattered gates
    const int ntiles = (E + 63) >> 6;
    const int eblocks = (ntiles + 3) / 4;           // 6250
    edge_kernel<<<dim3(eblocks), dim3(256), 0, stream>>>(
        e, We, be, src, dst, Q, K, e_out, s_sorted, src_sorted, rank, offsets, E);

    // 5) aggregate per node (one wave each)
    const int ablocks = (N * 64 + 255) / 256;
    aggregate_kernel<<<dim3(ablocks), dim3(256), 0, stream>>>(
        offsets, src_sorted, s_sorted, V, hout, N);
}